// Round 1
// 591.286 us; speedup vs baseline: 1.1013x; 1.1013x over previous
//
#include <hip/hip_runtime.h>

// R4: fix the zero-fill size. rocprof showed fillBufferAligned writing
// WRITE_SIZE = 2 GiB (= out_size * 4) at 6.2 TB/s -> 346 us. The output
// buffer is 512 MiB, so `out_size` is a BYTE count in this harness, and the
// old `out_size * sizeof(float)` memset wrote 4x the buffer (1.5 GiB OOB).
// Zeroing exactly out_size bytes cuts the fill to ~85 us at the same BW.
//
// Traffic accounting (corrected):
//   537 MB  mandatory zero-write of d_out (harness poisons it every launch)
//   ~64 MB  masked feature reads (cache-line granularity, np of 32 points)
//    ~4 MB  num_points + coords
//   ~13 MB  scattered 64 B voxel writes (aligned: channel stride = 16 floats)
//   ------  ~618 MB  ≈ 98 us at 6.3 TB/s.
// Compute kernel left untouched this round for clean attribution; its
// counters should surface in the next rocprof top-5.

__global__ void __launch_bounds__(256)
voxel_pointnet_kernel(
    const float* __restrict__ features,
    const int* __restrict__ num_points,
    const int* __restrict__ coords,
    const float* __restrict__ W1, const float* __restrict__ b1,
    const float* __restrict__ g1, const float* __restrict__ be1,
    const float* __restrict__ W2, const float* __restrict__ b2,
    const float* __restrict__ g2, const float* __restrict__ be2,
    const int* __restrict__ pB, const int* __restrict__ pGH,
    const int* __restrict__ pGW, const int* __restrict__ pGZ,
    float* __restrict__ out, int V, int P)
{
    __shared__ float sW1[64], sb1[16], sg1[16], sbe1[16];
    __shared__ float sW2[256], sb2[16], sg2[16], sbe2[16];
    int t = threadIdx.x;
    if (t < 64)  sW1[t] = W1[t];
    if (t < 256) sW2[t] = W2[t];
    if (t < 16) {
        sb1[t] = b1[t]; sg1[t] = g1[t]; sbe1[t] = be1[t];
        sb2[t] = b2[t]; sg2[t] = g2[t]; sbe2[t] = be2[t];
    }
    __syncthreads();

    int v = blockIdx.x * blockDim.x + t;
    if (v >= V) return;

    int np = num_points[v];
    np = np < 0 ? 0 : (np > P ? P : np);

    float hsum[16];
    #pragma unroll
    for (int j = 0; j < 16; j++) hsum[j] = 0.f;

    const float4* fp = (const float4*)(features + (size_t)v * P * 4);
    for (int p = 0; p < np; p++) {
        float4 f = fp[p];
        float h[16];
        float mu = 0.f;
        #pragma unroll
        for (int j = 0; j < 16; j++) {
            float acc = sb1[j];
            acc = fmaf(f.x, sW1[j],      acc);
            acc = fmaf(f.y, sW1[16 + j], acc);
            acc = fmaf(f.z, sW1[32 + j], acc);
            acc = fmaf(f.w, sW1[48 + j], acc);
            h[j] = acc;
            mu += acc;
        }
        mu *= 0.0625f;
        float var = 0.f;
        #pragma unroll
        for (int j = 0; j < 16; j++) { float d = h[j] - mu; var = fmaf(d, d, var); }
        var *= 0.0625f;
        float r = rsqrtf(var + 1e-5f);
        #pragma unroll
        for (int j = 0; j < 16; j++) {
            float val = fmaf((h[j] - mu) * r, sg1[j], sbe1[j]);
            hsum[j] += fmaxf(val, 0.f);
        }
    }

    // x = hsum @ W2 + np*b2, then LN(g2, be2)
    float fn = (float)np;
    float x[16];
    float mu = 0.f;
    #pragma unroll
    for (int j = 0; j < 16; j++) {
        float acc = fn * sb2[j];
        #pragma unroll
        for (int k = 0; k < 16; k++) acc = fmaf(hsum[k], sW2[k * 16 + j], acc);
        x[j] = acc;
        mu += acc;
    }
    mu *= 0.0625f;
    float var = 0.f;
    #pragma unroll
    for (int j = 0; j < 16; j++) { float d = x[j] - mu; var = fmaf(d, d, var); }
    var *= 0.0625f;
    float r = rsqrtf(var + 1e-5f);
    #pragma unroll
    for (int j = 0; j < 16; j++) x[j] = fmaf((x[j] - mu) * r, sg2[j], sbe2[j]);

    int B = *pB, GH = *pGH, GW = *pGW, GZ = *pGZ;
    int4 c = *(const int4*)(coords + (size_t)v * 4);
    // mode='drop': skip out-of-range coords
    if ((unsigned)c.x >= (unsigned)B || (unsigned)c.y >= (unsigned)GH ||
        (unsigned)c.z >= (unsigned)GW || (unsigned)c.w >= (unsigned)GZ) return;

    size_t o = ((((size_t)c.x * GH + c.y) * GW + c.z) * GZ + c.w) * 16;
    float4* op = (float4*)(out + o);   // 64 B aligned
    op[0] = make_float4(x[0],  x[1],  x[2],  x[3]);
    op[1] = make_float4(x[4],  x[5],  x[6],  x[7]);
    op[2] = make_float4(x[8],  x[9],  x[10], x[11]);
    op[3] = make_float4(x[12], x[13], x[14], x[15]);
}

extern "C" void kernel_launch(void* const* d_in, const int* in_sizes, int n_in,
                              void* d_out, int out_size, void* d_ws, size_t ws_size,
                              hipStream_t stream) {
    const float* features = (const float*)d_in[0];
    const int*   num_points = (const int*)d_in[1];
    const int*   coords   = (const int*)d_in[2];
    const float* W1  = (const float*)d_in[3];
    const float* b1  = (const float*)d_in[4];
    const float* g1  = (const float*)d_in[5];
    const float* be1 = (const float*)d_in[6];
    const float* W2  = (const float*)d_in[7];
    const float* b2  = (const float*)d_in[8];
    const float* g2  = (const float*)d_in[9];
    const float* be2 = (const float*)d_in[10];
    const int* pB  = (const int*)d_in[11];
    const int* pGH = (const int*)d_in[12];
    const int* pGW = (const int*)d_in[13];
    const int* pGZ = (const int*)d_in[14];
    float* out = (float*)d_out;

    int V  = in_sizes[1];
    int IN = in_sizes[3] / in_sizes[4];   // W1 is (IN,H); IN==4 expected
    int P  = in_sizes[0] / (V * IN);      // P==32 expected

    // out_size is a BYTE count (measured: old out_size*4 memset showed
    // WRITE_SIZE = 2 GiB = 4x the 512 MiB buffer). Zero exactly the buffer.
    hipMemsetAsync(d_out, 0, (size_t)out_size, stream);

    int blocks = (V + 255) / 256;
    voxel_pointnet_kernel<<<blocks, 256, 0, stream>>>(
        features, num_points, coords, W1, b1, g1, be1, W2, b2, g2, be2,
        pB, pGH, pGW, pGZ, out, V, P);
}